// Round 3
// baseline (104.046 us; speedup 1.0000x reference)
//
#include <hip/hip_runtime.h>
#include <hip/hip_bf16.h>

// Problem dims
#define X_B 8
#define X_C 64
#define X_H 64
#define X_W 64
#define X_S 12
// x index: (((b*64 + c)*64 + h)*64 + w)*12 + t
// h-row stride = 768 floats, channel stride = 49152 floats

// Scratch layout inside d_out (floats) — consumed before final output overwrites it:
//   [0,1600)                : Weff[c'*25 + tap]
//   [4096, 4096+16*393216)  : partial A_k, layout [q][tg][ (b*64+h)*64+w ][4t] (float4)
#define WEFF_OFF 0
#define PART_OFF 4096
#define PART_SZ  393216   // per q: 3 tg * 32768 bhw * 4 t
#define TG_SZ    131072   // 32768 * 4 floats
// d_ws: p[((b*64+h)*64+w)*12 + t]  (393216 floats = 1.57 MB)

// ---------------------------------------------------------------------------
// K1: fold 1x1-conv (key half of w1) into the 5x5 conv weights.
__global__ __launch_bounds__(256) void k_prep(const float* __restrict__ w1,
                                              const float* __restrict__ w2,
                                              float* __restrict__ weff) {
    int idx = blockIdx.x * 256 + threadIdx.x;
    if (idx >= 64 * 25) return;
    int cp = idx / 25, tap = idx % 25;
    float s = 0.f;
    for (int c = 0; c < 64; ++c)
        s = fmaf(w2[(64 + c) * 25 + tap], w1[(64 + c) * 64 + cp], s);
    weff[cp * 25 + tap] = s;
}

// ---------------------------------------------------------------------------
// K2 (v3): LDS-staged direct 5x5x64 conv producing partial A_k.
// Grid: 512 blocks = 8 b * 4 h-strips(16 rows) * 16 channel-groups(4 ch).
// Block: 256 thr = 64 w * 4 hq. Per channel: stage 20 input rows into LDS as
// 3 tg-planes of [row][w] float4 (16B/lane => conflict-free b128), w-halo
// pre-zeroed; compute 25 taps from LDS; thread owns 4 output rows x 12 t.
// Next channel's global loads are prefetched into regs during compute (T14).
#define PLANE 5444          // floats per tg plane: 20*272 + 4 pad
#define ROWP  272           // floats per row: 68 slots * 4
__global__ __launch_bounds__(256) void k_conv(const float* __restrict__ x,
                                              const float* __restrict__ weff,
                                              float* __restrict__ part) {
    __shared__ float lds[3 * PLANE];   // 65,328 B

    const int bid   = blockIdx.x;
    const int b     = bid & 7;
    const int strip = (bid >> 3) & 3;
    const int q     = bid >> 5;          // 0..15

    const int w  = threadIdx.x & 63;
    const int hq = threadIdx.x >> 6;     // 0..3
    const int r0 = strip * 16 - 2;       // global row of LDS row 0

    // zero the w-halo slots (w-index 0,1,66,67) once; never overwritten
    if (threadIdx.x < 240) {
        const int pl  = threadIdx.x / 80;
        const int rem = threadIdx.x % 80;
        const int row = rem >> 2;
        const int sl  = rem & 3;
        const int slot = (sl < 2) ? sl : 64 + sl;   // 0,1,66,67
        float4 z; z.x = 0.f; z.y = 0.f; z.z = 0.f; z.w = 0.f;
        *(float4*)(lds + pl * PLANE + row * ROWP + slot * 4) = z;
    }

    const float* xb = x + (size_t)(b * 64 + q * 4) * 49152;  // channel q*4

    float acc[4][12];
#pragma unroll
    for (int o = 0; o < 4; ++o)
#pragma unroll
        for (int j = 0; j < 12; ++j) acc[o][j] = 0.f;

    // prefetch channel 0 stage data into regs (coalesced: 16B/lane contiguous)
    float4 pf[15];
#pragma unroll
    for (int k = 0; k < 15; ++k) {
        const int rrr = k / 3, it = k % 3;
        const int r  = hq + rrr * 4;          // LDS row 0..19 (wave-uniform)
        const int rg = r0 + r;                // global row
        const int j  = it * 64 + w;           // f4 index within row (0..191)
        float4 v; v.x = 0.f; v.y = 0.f; v.z = 0.f; v.w = 0.f;
        if ((unsigned)rg < 64u) v = *(const float4*)(xb + rg * 768 + j * 4);
        pf[k] = v;
    }

    for (int ci = 0; ci < 4; ++ci) {
        // write staged channel to LDS (transpose to tg-planes)
#pragma unroll
        for (int k = 0; k < 15; ++k) {
            const int rrr = k / 3, it = k % 3;
            const int r = hq + rrr * 4;
            const unsigned j = (unsigned)(it * 64 + w);
            const unsigned wj = j / 3u;
            const unsigned tg = j - wj * 3u;
            *(float4*)(lds + tg * PLANE + r * ROWP + (wj + 2) * 4) = pf[k];
        }
        __syncthreads();

        // prefetch next channel while computing this one
        if (ci < 3) {
            const float* xc = xb + (size_t)(ci + 1) * 49152;
#pragma unroll
            for (int k = 0; k < 15; ++k) {
                const int rrr = k / 3, it = k % 3;
                const int r  = hq + rrr * 4;
                const int rg = r0 + r;
                const int j  = it * 64 + w;
                float4 v; v.x = 0.f; v.y = 0.f; v.z = 0.f; v.w = 0.f;
                if ((unsigned)rg < 64u) v = *(const float4*)(xc + rg * 768 + j * 4);
                pf[k] = v;
            }
        }

        // 25-tap conv from LDS; weights are wave-uniform scalar loads
        const float* wp = weff + (q * 4 + ci) * 25;
        float wgt[25];
#pragma unroll
        for (int k = 0; k < 25; ++k) wgt[k] = wp[k];

#pragma unroll
        for (int tg = 0; tg < 3; ++tg) {
            const float* lr0 = lds + tg * PLANE + (hq * 4) * ROWP + w * 4;
#pragma unroll
            for (int rr = 0; rr < 8; ++rr) {
                const float* lp = lr0 + rr * ROWP;
#pragma unroll
                for (int dw = 0; dw < 5; ++dw) {
                    float4 v = *(const float4*)(lp + dw * 4);   // slot w+dw, halo-safe
                    const int olo = (rr - 4 < 0) ? 0 : rr - 4;
                    const int ohi = (rr > 3) ? 3 : rr;
#pragma unroll
                    for (int oo = olo; oo <= ohi; ++oo) {
                        const float g = wgt[(rr - oo) * 5 + dw];
                        acc[oo][tg * 4 + 0] = fmaf(g, v.x, acc[oo][tg * 4 + 0]);
                        acc[oo][tg * 4 + 1] = fmaf(g, v.y, acc[oo][tg * 4 + 1]);
                        acc[oo][tg * 4 + 2] = fmaf(g, v.z, acc[oo][tg * 4 + 2]);
                        acc[oo][tg * 4 + 3] = fmaf(g, v.w, acc[oo][tg * 4 + 3]);
                    }
                }
            }
        }
        __syncthreads();   // protect LDS before next channel's writes
    }

    // store partials: [q][tg][bhw] float4 — fully coalesced
    float* pb = part + (size_t)q * PART_SZ;
#pragma unroll
    for (int oo = 0; oo < 4; ++oo) {
        const int h = strip * 16 + hq * 4 + oo;
        const int idx = (b * 64 + h) * 64 + w;
#pragma unroll
        for (int tg = 0; tg < 3; ++tg) {
            float4 st;
            st.x = acc[oo][tg * 4 + 0]; st.y = acc[oo][tg * 4 + 1];
            st.z = acc[oo][tg * 4 + 2]; st.w = acc[oo][tg * 4 + 3];
            *(float4*)(pb + (size_t)tg * TG_SZ + (size_t)idx * 4) = st;
        }
    }
}

// ---------------------------------------------------------------------------
// K3: sum the 16 channel-group partials, softmax over t (12), write p to ws.
__global__ __launch_bounds__(256) void k_soft(const float* __restrict__ part,
                                              float* __restrict__ p) {
    const int idx = blockIdx.x * 256 + threadIdx.x;  // (b,h,w) flat, 0..32767
    if (idx >= 32768) return;
    float v[12];
#pragma unroll
    for (int t = 0; t < 12; ++t) v[t] = 0.f;
#pragma unroll
    for (int qg = 0; qg < 16; ++qg) {
        const float* pp = part + (size_t)qg * PART_SZ;
#pragma unroll
        for (int tg = 0; tg < 3; ++tg) {
            float4 t0 = *(const float4*)(pp + (size_t)tg * TG_SZ + (size_t)idx * 4);
            v[tg * 4 + 0] += t0.x; v[tg * 4 + 1] += t0.y;
            v[tg * 4 + 2] += t0.z; v[tg * 4 + 3] += t0.w;
        }
    }
    float m = v[0];
#pragma unroll
    for (int t = 1; t < 12; ++t) m = fmaxf(m, v[t]);
    float s = 0.f;
#pragma unroll
    for (int t = 0; t < 12; ++t) { v[t] = __expf(v[t] - m); s += v[t]; }
    const float inv = 1.f / s;
#pragma unroll
    for (int t = 0; t < 12; ++t) v[t] *= inv;
    float* op = p + (size_t)idx * 12;
    float4 s0; s0.x = v[0]; s0.y = v[1]; s0.z = v[2];  s0.w = v[3];
    float4 s1; s1.x = v[4]; s1.y = v[5]; s1.z = v[6];  s1.w = v[7];
    float4 s2; s2.x = v[8]; s2.y = v[9]; s2.z = v[10]; s2.w = v[11];
    *(float4*)(op)     = s0;
    *(float4*)(op + 4) = s1;
    *(float4*)(op + 8) = s2;
}

// ---------------------------------------------------------------------------
// K4: out[b,c,h,w,s] = W1v · (sum_t p_t * x[:,t]) + b1v, broadcast over s.
// One block per (b,h): 512 threads = 64 w-lanes * 8 channel-groups.
__global__ __launch_bounds__(512) void k_out(const float* __restrict__ x,
                                             const float* __restrict__ w1,
                                             const float* __restrict__ b1,
                                             const float* __restrict__ p,
                                             float* __restrict__ out) {
    __shared__ float lds[64 * 65];   // [w][c], padded -> conflict-free

    const int b  = blockIdx.x >> 6;
    const int h  = blockIdx.x & 63;
    const int w  = threadIdx.x & 63;
    const int cg = threadIdx.x >> 6;     // 0..7

    const float* pp = p + (size_t)((b * 64 + h) * 64 + w) * 12;
    float pv[12];
    {
        float4 t0 = *(const float4*)(pp);
        float4 t1 = *(const float4*)(pp + 4);
        float4 t2 = *(const float4*)(pp + 8);
        pv[0] = t0.x; pv[1] = t0.y; pv[2]  = t0.z; pv[3]  = t0.w;
        pv[4] = t1.x; pv[5] = t1.y; pv[6]  = t1.z; pv[7]  = t1.w;
        pv[8] = t2.x; pv[9] = t2.y; pv[10] = t2.z; pv[11] = t2.w;
    }

    const float* xb0 = x + ((size_t)(b * 64 + cg * 8) * 64 + h) * 768 + w * 12;
#pragma unroll
    for (int j = 0; j < 8; ++j) {
        const float* xp = xb0 + (size_t)j * 49152;
        float4 u0 = *(const float4*)(xp);
        float4 u1 = *(const float4*)(xp + 4);
        float4 u2 = *(const float4*)(xp + 8);
        float s = 0.f;
        s = fmaf(pv[0], u0.x, s);  s = fmaf(pv[1], u0.y, s);
        s = fmaf(pv[2], u0.z, s);  s = fmaf(pv[3], u0.w, s);
        s = fmaf(pv[4], u1.x, s);  s = fmaf(pv[5], u1.y, s);
        s = fmaf(pv[6], u1.z, s);  s = fmaf(pv[7], u1.w, s);
        s = fmaf(pv[8], u2.x, s);  s = fmaf(pv[9], u2.y, s);
        s = fmaf(pv[10], u2.z, s); s = fmaf(pv[11], u2.w, s);
        lds[w * 65 + cg * 8 + j] = s;
    }
    __syncthreads();

    const float* w1v = w1 + 128 * 64 + cg * 8 * 64;
    float acc[8];
#pragma unroll
    for (int j = 0; j < 8; ++j) acc[j] = b1[128 + cg * 8 + j];
    for (int c2 = 0; c2 < 64; ++c2) {
        const float xv = lds[w * 65 + c2];
#pragma unroll
        for (int j = 0; j < 8; ++j)
            acc[j] = fmaf(w1v[j * 64 + c2], xv, acc[j]);
    }

#pragma unroll
    for (int j = 0; j < 8; ++j) {
        const int co = cg * 8 + j;
        float4 f; f.x = acc[j]; f.y = acc[j]; f.z = acc[j]; f.w = acc[j];
        float* op = out + ((size_t)(b * 64 + co) * 4096 + h * 64 + w) * 12;
        *(float4*)(op)     = f;
        *(float4*)(op + 4) = f;
        *(float4*)(op + 8) = f;
    }
}

// ---------------------------------------------------------------------------
extern "C" void kernel_launch(void* const* d_in, const int* in_sizes, int n_in,
                              void* d_out, int out_size, void* d_ws, size_t ws_size,
                              hipStream_t stream) {
    const float* x  = (const float*)d_in[0];
    const float* w1 = (const float*)d_in[1];
    const float* b1 = (const float*)d_in[2];
    const float* w2 = (const float*)d_in[3];
    // d_in[4] = b2: constant across the softmax axis -> cancels, unused.

    float* outp = (float*)d_out;
    float* weff = outp + WEFF_OFF;
    float* part = outp + PART_OFF;
    float* p    = (float*)d_ws;

    hipLaunchKernelGGL(k_prep, dim3(7),    dim3(256), 0, stream, w1, w2, weff);
    hipLaunchKernelGGL(k_conv, dim3(512),  dim3(256), 0, stream, x, weff, part);
    hipLaunchKernelGGL(k_soft, dim3(128),  dim3(256), 0, stream, part, p);
    hipLaunchKernelGGL(k_out,  dim3(512),  dim3(512), 0, stream, x, w1, b1, p, outp);
}

// Round 4
// 103.210 us; speedup vs baseline: 1.0081x; 1.0081x over previous
//
#include <hip/hip_runtime.h>
#include <hip/hip_bf16.h>

// Problem dims
#define X_B 8
#define X_C 64
#define X_H 64
#define X_W 64
#define X_S 12
// x index: (((b*64 + c)*64 + h)*64 + w)*12 + t
// h-row stride = 768 floats, channel stride = 49152 floats

// Scratch layout inside d_out (floats):
//   [0,1600)                : Weff[c'*25 + tap]
//   [4096, 4096+16*393216)  : partial A_k, layout [q][tg][ (b*64+h)*64+w ][4t] (float4)
#define WEFF_OFF 0
#define PART_OFF 4096
#define PART_SZ  393216   // per q: 3 tg * 32768 bhw * 4 t
#define TG_SZ    131072   // 32768 * 4 floats
// d_ws: p[((b*64+h)*64+w)*12 + t]  (393216 floats = 1.57 MB)

// ---------------------------------------------------------------------------
// K1: fold 1x1-conv (key half of w1) into the 5x5 conv weights.
__global__ __launch_bounds__(256) void k_prep(const float* __restrict__ w1,
                                              const float* __restrict__ w2,
                                              float* __restrict__ weff) {
    int idx = blockIdx.x * 256 + threadIdx.x;
    if (idx >= 64 * 25) return;
    int cp = idx / 25, tap = idx % 25;
    float s = 0.f;
    for (int c = 0; c < 64; ++c)
        s = fmaf(w2[(64 + c) * 25 + tap], w1[(64 + c) * 64 + cp], s);
    weff[cp * 25 + tap] = s;
}

// ---------------------------------------------------------------------------
// K2 (v4): LDS-staged direct 5x5x64 conv producing partial A_k.
// Same staging as v3 (3 tg-planes [row][w-slot] float4, zeroed w-halo,
// prefetch next channel into regs) but 512 threads/block: 64 w * 8 hq,
// thread owns 2 output rows x 12 t. 2 blocks/CU -> 16 waves/CU (was 8).
#define PLANE 5444          // floats per tg plane: 20*272 + 4 pad
#define ROWP  272           // floats per row: 68 slots * 4
#define NSTG  3840          // staged float4s per channel: 20 rows * 192
__global__ __launch_bounds__(512) void k_conv(const float* __restrict__ x,
                                              const float* __restrict__ weff,
                                              float* __restrict__ part) {
    __shared__ float lds[3 * PLANE];   // 65,328 B

    const int bid   = blockIdx.x;
    const int b     = bid & 7;
    const int strip = (bid >> 3) & 3;
    const int q     = bid >> 5;          // 0..15

    const int tid = threadIdx.x;
    const int w   = tid & 63;
    const int hq  = tid >> 6;            // 0..7
    const int r0  = strip * 16 - 2;      // global row of LDS row 0

    // zero the w-halo slots (w-slot 0,1,66,67) once; never overwritten
    if (tid < 240) {
        const int pl  = tid / 80;
        const int rem = tid % 80;
        const int row = rem >> 2;
        const int sl  = rem & 3;
        const int slot = (sl < 2) ? sl : 64 + sl;   // 0,1,66,67
        float4 z; z.x = 0.f; z.y = 0.f; z.z = 0.f; z.w = 0.f;
        *(float4*)(lds + pl * PLANE + row * ROWP + slot * 4) = z;
    }

    const float* xb = x + (size_t)(b * 64 + q * 4) * 49152;  // channel q*4

    float acc[2][12];
#pragma unroll
    for (int o = 0; o < 2; ++o)
#pragma unroll
        for (int j = 0; j < 12; ++j) acc[o][j] = 0.f;

    // prefetch channel 0 (coalesced 16B/lane; OOB rows -> zero)
    float4 pf[8];
#pragma unroll
    for (int k = 0; k < 8; ++k) {
        const int i = tid + k * 512;
        float4 v; v.x = 0.f; v.y = 0.f; v.z = 0.f; v.w = 0.f;
        if (i < NSTG) {
            const int row = i / 192;
            const int j   = i - row * 192;
            const int rg  = r0 + row;
            if ((unsigned)rg < 64u) v = *(const float4*)(xb + rg * 768 + j * 4);
        }
        pf[k] = v;
    }

    for (int ci = 0; ci < 4; ++ci) {
        // write staged channel to LDS (transpose to tg-planes)
#pragma unroll
        for (int k = 0; k < 8; ++k) {
            const int i = tid + k * 512;
            if (i < NSTG) {
                const int row = i / 192;
                const unsigned j = (unsigned)(i - row * 192);
                const unsigned wj = j / 3u;
                const unsigned tg = j - wj * 3u;
                *(float4*)(lds + tg * PLANE + row * ROWP + (wj + 2) * 4) = pf[k];
            }
        }
        __syncthreads();

        // prefetch next channel while computing this one
        if (ci < 3) {
            const float* xc = xb + (size_t)(ci + 1) * 49152;
#pragma unroll
            for (int k = 0; k < 8; ++k) {
                const int i = tid + k * 512;
                float4 v; v.x = 0.f; v.y = 0.f; v.z = 0.f; v.w = 0.f;
                if (i < NSTG) {
                    const int row = i / 192;
                    const int j   = i - row * 192;
                    const int rg  = r0 + row;
                    if ((unsigned)rg < 64u) v = *(const float4*)(xc + rg * 768 + j * 4);
                }
                pf[k] = v;
            }
        }

        // 25-tap conv from LDS; weights are wave-uniform scalar loads
        const float* wp = weff + (q * 4 + ci) * 25;
        float wgt[25];
#pragma unroll
        for (int k = 0; k < 25; ++k) wgt[k] = wp[k];

#pragma unroll
        for (int tg = 0; tg < 3; ++tg) {
            const float* lr0 = lds + tg * PLANE + (hq * 2) * ROWP + w * 4;
#pragma unroll
            for (int rr = 0; rr < 6; ++rr) {       // LDS rows hq*2 .. hq*2+5
                const float* lp = lr0 + rr * ROWP;
#pragma unroll
                for (int dw = 0; dw < 5; ++dw) {
                    float4 v = *(const float4*)(lp + dw * 4);   // slot w+dw, halo-safe
                    const int olo = (rr - 4 < 0) ? 0 : rr - 4;
                    const int ohi = (rr > 1) ? 1 : rr;
#pragma unroll
                    for (int oo = olo; oo <= ohi; ++oo) {
                        const float g = wgt[(rr - oo) * 5 + dw];
                        acc[oo][tg * 4 + 0] = fmaf(g, v.x, acc[oo][tg * 4 + 0]);
                        acc[oo][tg * 4 + 1] = fmaf(g, v.y, acc[oo][tg * 4 + 1]);
                        acc[oo][tg * 4 + 2] = fmaf(g, v.z, acc[oo][tg * 4 + 2]);
                        acc[oo][tg * 4 + 3] = fmaf(g, v.w, acc[oo][tg * 4 + 3]);
                    }
                }
            }
        }
        __syncthreads();   // protect LDS before next channel's writes
    }

    // store partials: [q][tg][bhw] float4 — fully coalesced
    float* pb = part + (size_t)q * PART_SZ;
#pragma unroll
    for (int oo = 0; oo < 2; ++oo) {
        const int h = strip * 16 + hq * 2 + oo;
        const int idx = (b * 64 + h) * 64 + w;
#pragma unroll
        for (int tg = 0; tg < 3; ++tg) {
            float4 st;
            st.x = acc[oo][tg * 4 + 0]; st.y = acc[oo][tg * 4 + 1];
            st.z = acc[oo][tg * 4 + 2]; st.w = acc[oo][tg * 4 + 3];
            *(float4*)(pb + (size_t)tg * TG_SZ + (size_t)idx * 4) = st;
        }
    }
}

// ---------------------------------------------------------------------------
// K3: sum the 16 channel-group partials, softmax over t (12), write p to ws.
__global__ __launch_bounds__(256) void k_soft(const float* __restrict__ part,
                                              float* __restrict__ p) {
    const int idx = blockIdx.x * 256 + threadIdx.x;  // (b,h,w) flat, 0..32767
    if (idx >= 32768) return;
    float v[12];
#pragma unroll
    for (int t = 0; t < 12; ++t) v[t] = 0.f;
#pragma unroll
    for (int qg = 0; qg < 16; ++qg) {
        const float* pp = part + (size_t)qg * PART_SZ;
#pragma unroll
        for (int tg = 0; tg < 3; ++tg) {
            float4 t0 = *(const float4*)(pp + (size_t)tg * TG_SZ + (size_t)idx * 4);
            v[tg * 4 + 0] += t0.x; v[tg * 4 + 1] += t0.y;
            v[tg * 4 + 2] += t0.z; v[tg * 4 + 3] += t0.w;
        }
    }
    float m = v[0];
#pragma unroll
    for (int t = 1; t < 12; ++t) m = fmaxf(m, v[t]);
    float s = 0.f;
#pragma unroll
    for (int t = 0; t < 12; ++t) { v[t] = __expf(v[t] - m); s += v[t]; }
    const float inv = 1.f / s;
#pragma unroll
    for (int t = 0; t < 12; ++t) v[t] *= inv;
    float* op = p + (size_t)idx * 12;
    float4 s0; s0.x = v[0]; s0.y = v[1]; s0.z = v[2];  s0.w = v[3];
    float4 s1; s1.x = v[4]; s1.y = v[5]; s1.z = v[6];  s1.w = v[7];
    float4 s2; s2.x = v[8]; s2.y = v[9]; s2.z = v[10]; s2.w = v[11];
    *(float4*)(op)     = s0;
    *(float4*)(op + 4) = s1;
    *(float4*)(op + 8) = s2;
}

// ---------------------------------------------------------------------------
// K4: out[b,c,h,w,s] = W1v · (sum_t p_t * x[:,t]) + b1v, broadcast over s.
// One block per (b,h): 512 threads = 64 w-lanes * 8 channel-groups.
__global__ __launch_bounds__(512) void k_out(const float* __restrict__ x,
                                             const float* __restrict__ w1,
                                             const float* __restrict__ b1,
                                             const float* __restrict__ p,
                                             float* __restrict__ out) {
    __shared__ float lds[64 * 65];   // [w][c], padded -> conflict-free

    const int b  = blockIdx.x >> 6;
    const int h  = blockIdx.x & 63;
    const int w  = threadIdx.x & 63;
    const int cg = threadIdx.x >> 6;     // 0..7

    const float* pp = p + (size_t)((b * 64 + h) * 64 + w) * 12;
    float pv[12];
    {
        float4 t0 = *(const float4*)(pp);
        float4 t1 = *(const float4*)(pp + 4);
        float4 t2 = *(const float4*)(pp + 8);
        pv[0] = t0.x; pv[1] = t0.y; pv[2]  = t0.z; pv[3]  = t0.w;
        pv[4] = t1.x; pv[5] = t1.y; pv[6]  = t1.z; pv[7]  = t1.w;
        pv[8] = t2.x; pv[9] = t2.y; pv[10] = t2.z; pv[11] = t2.w;
    }

    const float* xb0 = x + ((size_t)(b * 64 + cg * 8) * 64 + h) * 768 + w * 12;
#pragma unroll
    for (int j = 0; j < 8; ++j) {
        const float* xp = xb0 + (size_t)j * 49152;
        float4 u0 = *(const float4*)(xp);
        float4 u1 = *(const float4*)(xp + 4);
        float4 u2 = *(const float4*)(xp + 8);
        float s = 0.f;
        s = fmaf(pv[0], u0.x, s);  s = fmaf(pv[1], u0.y, s);
        s = fmaf(pv[2], u0.z, s);  s = fmaf(pv[3], u0.w, s);
        s = fmaf(pv[4], u1.x, s);  s = fmaf(pv[5], u1.y, s);
        s = fmaf(pv[6], u1.z, s);  s = fmaf(pv[7], u1.w, s);
        s = fmaf(pv[8], u2.x, s);  s = fmaf(pv[9], u2.y, s);
        s = fmaf(pv[10], u2.z, s); s = fmaf(pv[11], u2.w, s);
        lds[w * 65 + cg * 8 + j] = s;
    }
    __syncthreads();

    const float* w1v = w1 + 128 * 64 + cg * 8 * 64;
    float acc[8];
#pragma unroll
    for (int j = 0; j < 8; ++j) acc[j] = b1[128 + cg * 8 + j];
    for (int c2 = 0; c2 < 64; ++c2) {
        const float xv = lds[w * 65 + c2];
#pragma unroll
        for (int j = 0; j < 8; ++j)
            acc[j] = fmaf(w1v[j * 64 + c2], xv, acc[j]);
    }

#pragma unroll
    for (int j = 0; j < 8; ++j) {
        const int co = cg * 8 + j;
        float4 f; f.x = acc[j]; f.y = acc[j]; f.z = acc[j]; f.w = acc[j];
        float* op = out + ((size_t)(b * 64 + co) * 4096 + h * 64 + w) * 12;
        *(float4*)(op)     = f;
        *(float4*)(op + 4) = f;
        *(float4*)(op + 8) = f;
    }
}

// ---------------------------------------------------------------------------
extern "C" void kernel_launch(void* const* d_in, const int* in_sizes, int n_in,
                              void* d_out, int out_size, void* d_ws, size_t ws_size,
                              hipStream_t stream) {
    const float* x  = (const float*)d_in[0];
    const float* w1 = (const float*)d_in[1];
    const float* b1 = (const float*)d_in[2];
    const float* w2 = (const float*)d_in[3];
    // d_in[4] = b2: constant across the softmax axis -> cancels, unused.

    float* outp = (float*)d_out;
    float* weff = outp + WEFF_OFF;
    float* part = outp + PART_OFF;
    float* p    = (float*)d_ws;

    hipLaunchKernelGGL(k_prep, dim3(7),    dim3(256), 0, stream, w1, w2, weff);
    hipLaunchKernelGGL(k_conv, dim3(512),  dim3(512), 0, stream, x, weff, part);
    hipLaunchKernelGGL(k_soft, dim3(128),  dim3(256), 0, stream, part, p);
    hipLaunchKernelGGL(k_out,  dim3(512),  dim3(512), 0, stream, x, w1, b1, p, outp);
}